// Round 6
// baseline (433.460 us; speedup 1.0000x reference)
//
#include <hip/hip_runtime.h>

// ---------- common types ----------
typedef float  f32x4  __attribute__((ext_vector_type(4)));
typedef short  bf16x8 __attribute__((ext_vector_type(8)));

#define MFMA16(a, b, c) __builtin_amdgcn_mfma_f32_16x16x32_bf16((a), (b), (c), 0, 0, 0)

__device__ __forceinline__ short f2bf(float f) {
    union { float f; unsigned u; } a; a.f = f;
    unsigned r = a.u + 0x7fffu + ((a.u >> 16) & 1u);  // RNE
    return (short)(r >> 16);
}
__device__ __forceinline__ float bf2f(unsigned short u) {
    union { unsigned u; float f; } a; a.u = ((unsigned)u) << 16; return a.f;
}

// sizes
#define Bb   8
#define Nn   1024
#define DIM  768
#define HH   12
#define HD   64
#define INNER 768
#define SCALE 0.125f   // folded into Q at the QKV epilogue (pow2 -> exact in bf16)

// ---------- prep kernels ----------
__global__ void cast_to_bf16(const float* __restrict__ in, short* __restrict__ out, int n4) {
    int i = blockIdx.x * 256 + threadIdx.x;
    if (i >= n4) return;
    float4 f = reinterpret_cast<const float4*>(in)[i];
    unsigned lo = (unsigned)(unsigned short)f2bf(f.x) | ((unsigned)(unsigned short)f2bf(f.y) << 16);
    unsigned hi = (unsigned)(unsigned short)f2bf(f.z) | ((unsigned)(unsigned short)f2bf(f.w) << 16);
    reinterpret_cast<uint2*>(out)[i] = make_uint2(lo, hi);
}

// wt[c][k] = w[k][c]; w is [rows=K][cols], wt is [cols][K]
__global__ void transpose_cast(const float* __restrict__ w, short* __restrict__ wt,
                               int rows, int cols) {
    int idx = blockIdx.x * 256 + threadIdx.x;
    if (idx >= rows * cols) return;
    int c = idx / rows;
    int k = idx - c * rows;
    wt[idx] = f2bf(w[k * cols + c]);
}

// ---------- GEMM: C[M,N] = A[M,K] @ Bt[N,K]^T ----------
template <int MODE>
__global__ __launch_bounds__(256, 2)
void gemm128(const short* __restrict__ A, const short* __restrict__ Bt, int K,
             short* __restrict__ qb, short* __restrict__ kb, short* __restrict__ vtb,
             float* __restrict__ outp, const float* __restrict__ bias) {
    __shared__ __align__(16) short As[128 * 40];
    __shared__ __align__(16) short Bs[128 * 40];

    const int tid  = threadIdx.x;
    const int lane = tid & 63, wv = tid >> 6;
    const int wrow = wv >> 1, wcol = wv & 1;
    const int quad = lane >> 4, l16 = lane & 15;
    const int m0 = blockIdx.y * 128, n0 = blockIdx.x * 128;

    const int srow = tid >> 1;
    const int soff = (tid & 1) * 16;

    f32x4 acc[4][4];
#pragma unroll
    for (int i = 0; i < 4; i++)
#pragma unroll
        for (int j = 0; j < 4; j++) acc[i][j] = (f32x4){0.f, 0.f, 0.f, 0.f};

    for (int kc = 0; kc < K; kc += 32) {
        const uint4 a0 = *reinterpret_cast<const uint4*>(A + (size_t)(m0 + srow) * K + kc + soff);
        const uint4 a1 = *reinterpret_cast<const uint4*>(A + (size_t)(m0 + srow) * K + kc + soff + 8);
        const uint4 b0 = *reinterpret_cast<const uint4*>(Bt + (size_t)(n0 + srow) * K + kc + soff);
        const uint4 b1 = *reinterpret_cast<const uint4*>(Bt + (size_t)(n0 + srow) * K + kc + soff + 8);
        __syncthreads();
        *reinterpret_cast<uint4*>(&As[srow * 40 + soff])     = a0;
        *reinterpret_cast<uint4*>(&As[srow * 40 + soff + 8]) = a1;
        *reinterpret_cast<uint4*>(&Bs[srow * 40 + soff])     = b0;
        *reinterpret_cast<uint4*>(&Bs[srow * 40 + soff + 8]) = b1;
        __syncthreads();

        bf16x8 af[4], bfr[4];
#pragma unroll
        for (int t = 0; t < 4; t++)
            af[t] = *reinterpret_cast<bf16x8*>(&As[(wrow * 64 + t * 16 + l16) * 40 + quad * 8]);
#pragma unroll
        for (int t = 0; t < 4; t++)
            bfr[t] = *reinterpret_cast<bf16x8*>(&Bs[(wcol * 64 + t * 16 + l16) * 40 + quad * 8]);
#pragma unroll
        for (int rt = 0; rt < 4; rt++)
#pragma unroll
            for (int ct = 0; ct < 4; ct++)
                acc[rt][ct] = MFMA16(af[rt], bfr[ct], acc[rt][ct]);
    }

    // epilogue: C/D layout col=lane&15, row=quad*4+reg
#pragma unroll
    for (int rt = 0; rt < 4; rt++) {
#pragma unroll
        for (int ct = 0; ct < 4; ct++) {
            const int c = n0 + wcol * 64 + ct * 16 + l16;
#pragma unroll
            for (int reg = 0; reg < 4; reg++) {
                const int r = m0 + wrow * 64 + rt * 16 + quad * 4 + reg;
                const float v = acc[rt][ct][reg];
                if (MODE == 0) {
                    const int b = r >> 10, n = r & 1023;
                    const int which = (c >= 1536) ? 2 : (c >= 768 ? 1 : 0);
                    const int cc = c - which * 768;
                    const int h = cc >> 6, d = cc & 63;
                    const int bh = b * HH + h;
                    if (which == 0)      qb[(bh << 16) + (n << 6) + d] = f2bf(v * SCALE);
                    else if (which == 1) kb[(bh << 16) + (n << 6) + d] = f2bf(v);
                    else                 vtb[(bh << 16) + (d << 10) + n] = f2bf(v);
                } else {
                    outp[(size_t)r * 768 + c] = v + bias[c];
                }
            }
        }
    }
}

// ---------- attention pass 1: barrier-free denominator, 50% occupancy ----------
// Wave tile 32n x 64m, NO LDS, NO barriers. 4096 waves / 1024 blocks =
// 4 blocks/CU (launch_bounds(256,4) -> VGPR cap 128). Q/K fragments straight
// from L2 (per-b Q+K = 3 MB fits the XCD L2; b = bid&7). Q pre-scaled, so
// den += exp(s) directly. Output inv_den bf16 in raw C-layout tiles.
__global__ __launch_bounds__(256, 4)
void attn_den4(const short* __restrict__ qb, const short* __restrict__ kb,
               short* __restrict__ invp) {
    const int tid = threadIdx.x, lane = tid & 63, wv = tid >> 6;
    const int quad = lane >> 4, l16 = lane & 15;
    const int b = blockIdx.x & 7;
    const int widx = ((blockIdx.x >> 3) << 2) + wv;   // 0..511
    const int n0 = (widx >> 4) << 5;                  // 32 n-strips
    const int m0 = (widx & 15) << 6;                  // 16 m64-chunks

    f32x4 den[2][4];
#pragma unroll
    for (int i = 0; i < 2; i++)
#pragma unroll
        for (int j = 0; j < 4; j++) den[i][j] = (f32x4){0.f, 0.f, 0.f, 0.f};
    const f32x4 z = (f32x4){0.f, 0.f, 0.f, 0.f};

    for (int h = 0; h < HH; h++) {
        const short* qp = qb + ((b * HH + h) << 16);
        const short* kp = kb + ((b * HH + h) << 16);
        bf16x8 qf[2][2], kf[4][2];
#pragma unroll
        for (int nt = 0; nt < 2; nt++) {
            const short* p = qp + ((n0 + nt * 16 + l16) << 6) + quad * 8;
            qf[nt][0] = *reinterpret_cast<const bf16x8*>(p);
            qf[nt][1] = *reinterpret_cast<const bf16x8*>(p + 32);
        }
#pragma unroll
        for (int mt = 0; mt < 4; mt++) {
            const short* p = kp + ((m0 + mt * 16 + l16) << 6) + quad * 8;
            kf[mt][0] = *reinterpret_cast<const bf16x8*>(p);
            kf[mt][1] = *reinterpret_cast<const bf16x8*>(p + 32);
        }
#pragma unroll
        for (int nt = 0; nt < 2; nt++)
#pragma unroll
            for (int mt = 0; mt < 4; mt++) {
                f32x4 s = MFMA16(qf[nt][0], kf[mt][0], z);
                s = MFMA16(qf[nt][1], kf[mt][1], s);
#pragma unroll
                for (int r = 0; r < 4; r++) den[nt][mt][r] += __expf(s[r]);
            }
    }

#pragma unroll
    for (int nt = 0; nt < 2; nt++)
#pragma unroll
        for (int mt = 0; mt < 4; mt++) {
            const int ntg = (n0 >> 4) + nt;
            const int mtg = (m0 >> 4) + mt;
            ushort4 o;
            o.x = (unsigned short)f2bf(1.0f / den[nt][mt][0]);
            o.y = (unsigned short)f2bf(1.0f / den[nt][mt][1]);
            o.z = (unsigned short)f2bf(1.0f / den[nt][mt][2]);
            o.w = (unsigned short)f2bf(1.0f / den[nt][mt][3]);
            *reinterpret_cast<ushort4*>(&invp[(((b * 64 + ntg) * 64 + mtg) * 64 + lane) * 4]) = o;
        }
}

// ---------- attention pass 2: barrier-free recompute-S + PV, 6 blocks/CU ----------
// Wave = (b, h, n16): 6144 waves / 1536 blocks. NO __syncthreads: K/V/invp
// fragments straight from L2; P round-trips through a wave-PRIVATE LDS stash
// (intra-wave RAW ordered by __threadfence_block). O = 16 VGPR.
__global__ __launch_bounds__(256, 6)
void attn_pv4(const short* __restrict__ qb, const short* __restrict__ kb,
              const short* __restrict__ vtb, const short* __restrict__ invp,
              short* __restrict__ attn_out) {
    __shared__ __align__(16) short Ps[4][16 * 40];  // per-wave [n16][m32], stride 40

    const int tid = threadIdx.x, lane = tid & 63, wv = tid >> 6;
    const int quad = lane >> 4, l16 = lane & 15;
    const int b = blockIdx.x & 7;
    const int r = blockIdx.x >> 3;       // 0..191
    const int strip = r / 12;            // 0..15 (n64 strip)
    const int h = r - strip * 12;
    const int n0 = (strip << 6) + (wv << 4);
    const int ntg = n0 >> 4;
    const int bh = b * HH + h;

    // Q A-frag (pre-scaled by 1/8)
    const short* qp = qb + (bh << 16) + ((n0 + l16) << 6) + quad * 8;
    const bf16x8 aq0 = *reinterpret_cast<const bf16x8*>(qp);
    const bf16x8 aq1 = *reinterpret_cast<const bf16x8*>(qp + 32);

    const f32x4 z = (f32x4){0.f, 0.f, 0.f, 0.f};
    f32x4 O[4];
#pragma unroll
    for (int d = 0; d < 4; d++) O[d] = z;

    for (int it = 0; it < 32; it++) {
        const int m0 = it << 5;

        // K frags for two m16 halves
        bf16x8 kf[2][2];
#pragma unroll
        for (int mh = 0; mh < 2; mh++) {
            const short* kp = kb + (bh << 16) + ((m0 + mh * 16 + l16) << 6) + quad * 8;
            kf[mh][0] = *reinterpret_cast<const bf16x8*>(kp);
            kf[mh][1] = *reinterpret_cast<const bf16x8*>(kp + 32);
        }
        // V B-frags: B[k=m=quad*8+j][d=l16] for 4 d16 chunks
        bf16x8 vf[4];
#pragma unroll
        for (int dch = 0; dch < 4; dch++)
            vf[dch] = *reinterpret_cast<const bf16x8*>(
                vtb + (bh << 16) + ((dch * 16 + l16) << 10) + m0 + quad * 8);

        // S, P = exp(s)*inv -> wave-private stash
#pragma unroll
        for (int mh = 0; mh < 2; mh++) {
            f32x4 s = MFMA16(aq0, kf[mh][0], z);
            s = MFMA16(aq1, kf[mh][1], s);
            const int mt = (m0 >> 4) + mh;
            const ushort4 iv = *reinterpret_cast<const ushort4*>(
                &invp[(((b * 64 + ntg) * 64 + mt) * 64 + lane) * 4]);
            Ps[wv][(quad * 4 + 0) * 40 + mh * 16 + l16] = f2bf(__expf(s[0]) * bf2f(iv.x));
            Ps[wv][(quad * 4 + 1) * 40 + mh * 16 + l16] = f2bf(__expf(s[1]) * bf2f(iv.y));
            Ps[wv][(quad * 4 + 2) * 40 + mh * 16 + l16] = f2bf(__expf(s[2]) * bf2f(iv.z));
            Ps[wv][(quad * 4 + 3) * 40 + mh * 16 + l16] = f2bf(__expf(s[3]) * bf2f(iv.w));
        }
        __threadfence_block();  // intra-wave cross-lane RAW on Ps

        // PV: A-frag = P[n=l16][k=quad*8+j] covers full m32 in one b128 read
        const bf16x8 pa = *reinterpret_cast<bf16x8*>(&Ps[wv][l16 * 40 + quad * 8]);
#pragma unroll
        for (int dch = 0; dch < 4; dch++)
            O[dch] = MFMA16(pa, vf[dch], O[dch]);
    }

    // epilogue: O C-layout row=quad*4+reg (n), col=l16 (d within chunk)
#pragma unroll
    for (int dch = 0; dch < 4; dch++) {
        const int col = h * 64 + dch * 16 + l16;
#pragma unroll
        for (int reg = 0; reg < 4; reg++) {
            const int n = n0 + quad * 4 + reg;
            attn_out[(size_t)((b << 10) + n) * 768 + col] = f2bf(O[dch][reg]);
        }
    }
}

// ---------- launch ----------
extern "C" void kernel_launch(void* const* d_in, const int* in_sizes, int n_in,
                              void* d_out, int out_size, void* d_ws, size_t ws_size,
                              hipStream_t stream) {
    const float* x     = (const float*)d_in[0];
    const float* w_qkv = (const float*)d_in[1];
    const float* w_out = (const float*)d_in[2];
    const float* b_out = (const float*)d_in[3];
    float* out = (float*)d_out;

    short* xb   = (short*)d_ws;                 // [8192][768]
    short* wT1  = xb  + 8192 * 768;             // [2304][768]
    short* wT2  = wT1 + 2304 * 768;             // [768][768]
    short* qb   = wT2 + 768 * 768;              // [b][h][n][d]  (Q pre-scaled by 1/8)
    short* kb   = qb  + 96 * 65536;
    short* vtb  = kb  + 96 * 65536;             // [b][h][d][n]
    short* attn = vtb + 96 * 65536;             // [8192][768]
    short* invp = attn + 8192 * 768;            // [b][nt][mt][lane][4]

    cast_to_bf16<<<6144, 256, 0, stream>>>(x, xb, (8192 * 768) / 4);
    transpose_cast<<<(2304 * 768) / 256, 256, 0, stream>>>(w_qkv, wT1, 768, 2304);
    transpose_cast<<<(768 * 768) / 256, 256, 0, stream>>>(w_out, wT2, 768, 768);

    gemm128<0><<<dim3(2304 / 128, 8192 / 128), 256, 0, stream>>>(
        xb, wT1, 768, qb, kb, vtb, nullptr, nullptr);

    attn_den4<<<1024, 256, 0, stream>>>(qb, kb, invp);
    attn_pv4<<<1536, 256, 0, stream>>>(qb, kb, vtb, invp, attn);

    gemm128<1><<<dim3(768 / 128, 8192 / 128), 256, 0, stream>>>(
        attn, wT2, 768, nullptr, nullptr, nullptr, out, b_out);
}

// Round 7
// 374.231 us; speedup vs baseline: 1.1583x; 1.1583x over previous
//
#include <hip/hip_runtime.h>

// ---------- common types ----------
typedef float  f32x4  __attribute__((ext_vector_type(4)));
typedef short  bf16x8 __attribute__((ext_vector_type(8)));
typedef short  bf16x4 __attribute__((ext_vector_type(4)));

#define MFMA16(a, b, c) __builtin_amdgcn_mfma_f32_16x16x32_bf16((a), (b), (c), 0, 0, 0)
// K=16 MFMA: A,B = 4 bf16 (2 VGPR). B-operand layout (col=lane&15, k=quad*4+j)
// == C/D layout of a previous MFMA -> lets S^T feed PV with no transpose.
#define MFMA16K16(a, b, c) __builtin_amdgcn_mfma_f32_16x16x16bf16_1k((a), (b), (c), 0, 0, 0)

__device__ __forceinline__ short f2bf(float f) {
    union { float f; unsigned u; } a; a.f = f;
    unsigned r = a.u + 0x7fffu + ((a.u >> 16) & 1u);  // RNE
    return (short)(r >> 16);
}
__device__ __forceinline__ float bf2f(unsigned short u) {
    union { unsigned u; float f; } a; a.u = ((unsigned)u) << 16; return a.f;
}

// sizes
#define Bb   8
#define Nn   1024
#define DIM  768
#define HH   12
#define HD   64
#define INNER 768
#define SCALE 0.125f   // folded into Q at the QKV epilogue (pow2 -> exact in bf16)

// ---------- prep kernels ----------
__global__ void cast_to_bf16(const float* __restrict__ in, short* __restrict__ out, int n4) {
    int i = blockIdx.x * 256 + threadIdx.x;
    if (i >= n4) return;
    float4 f = reinterpret_cast<const float4*>(in)[i];
    unsigned lo = (unsigned)(unsigned short)f2bf(f.x) | ((unsigned)(unsigned short)f2bf(f.y) << 16);
    unsigned hi = (unsigned)(unsigned short)f2bf(f.z) | ((unsigned)(unsigned short)f2bf(f.w) << 16);
    reinterpret_cast<uint2*>(out)[i] = make_uint2(lo, hi);
}

// wt[c][k] = w[k][c]
__global__ void transpose_cast(const float* __restrict__ w, short* __restrict__ wt,
                               int rows, int cols) {
    int idx = blockIdx.x * 256 + threadIdx.x;
    if (idx >= rows * cols) return;
    int c = idx / rows;
    int k = idx - c * rows;
    wt[idx] = f2bf(w[k * cols + c]);
}

// ---------- GEMM: C[M,N] = A[M,K] @ Bt[N,K]^T ----------
template <int MODE>
__global__ __launch_bounds__(256, 2)
void gemm128(const short* __restrict__ A, const short* __restrict__ Bt, int K,
             short* __restrict__ qb, short* __restrict__ kb, short* __restrict__ vtb,
             float* __restrict__ outp, const float* __restrict__ bias) {
    __shared__ __align__(16) short As[128 * 40];
    __shared__ __align__(16) short Bs[128 * 40];

    const int tid  = threadIdx.x;
    const int lane = tid & 63, wv = tid >> 6;
    const int wrow = wv >> 1, wcol = wv & 1;
    const int quad = lane >> 4, l16 = lane & 15;
    const int m0 = blockIdx.y * 128, n0 = blockIdx.x * 128;

    const int srow = tid >> 1;
    const int soff = (tid & 1) * 16;

    f32x4 acc[4][4];
#pragma unroll
    for (int i = 0; i < 4; i++)
#pragma unroll
        for (int j = 0; j < 4; j++) acc[i][j] = (f32x4){0.f, 0.f, 0.f, 0.f};

    for (int kc = 0; kc < K; kc += 32) {
        const uint4 a0 = *reinterpret_cast<const uint4*>(A + (size_t)(m0 + srow) * K + kc + soff);
        const uint4 a1 = *reinterpret_cast<const uint4*>(A + (size_t)(m0 + srow) * K + kc + soff + 8);
        const uint4 b0 = *reinterpret_cast<const uint4*>(Bt + (size_t)(n0 + srow) * K + kc + soff);
        const uint4 b1 = *reinterpret_cast<const uint4*>(Bt + (size_t)(n0 + srow) * K + kc + soff + 8);
        __syncthreads();
        *reinterpret_cast<uint4*>(&As[srow * 40 + soff])     = a0;
        *reinterpret_cast<uint4*>(&As[srow * 40 + soff + 8]) = a1;
        *reinterpret_cast<uint4*>(&Bs[srow * 40 + soff])     = b0;
        *reinterpret_cast<uint4*>(&Bs[srow * 40 + soff + 8]) = b1;
        __syncthreads();

        bf16x8 af[4], bfr[4];
#pragma unroll
        for (int t = 0; t < 4; t++)
            af[t] = *reinterpret_cast<bf16x8*>(&As[(wrow * 64 + t * 16 + l16) * 40 + quad * 8]);
#pragma unroll
        for (int t = 0; t < 4; t++)
            bfr[t] = *reinterpret_cast<bf16x8*>(&Bs[(wcol * 64 + t * 16 + l16) * 40 + quad * 8]);
#pragma unroll
        for (int rt = 0; rt < 4; rt++)
#pragma unroll
            for (int ct = 0; ct < 4; ct++)
                acc[rt][ct] = MFMA16(af[rt], bfr[ct], acc[rt][ct]);
    }

    // epilogue: C/D layout col=lane&15, row=quad*4+reg
#pragma unroll
    for (int rt = 0; rt < 4; rt++) {
#pragma unroll
        for (int ct = 0; ct < 4; ct++) {
            const int c = n0 + wcol * 64 + ct * 16 + l16;
#pragma unroll
            for (int reg = 0; reg < 4; reg++) {
                const int r = m0 + wrow * 64 + rt * 16 + quad * 4 + reg;
                const float v = acc[rt][ct][reg];
                if (MODE == 0) {
                    const int b = r >> 10, n = r & 1023;
                    const int which = (c >= 1536) ? 2 : (c >= 768 ? 1 : 0);
                    const int cc = c - which * 768;
                    const int h = cc >> 6, d = cc & 63;
                    const int bh = b * HH + h;
                    if (which == 0)      qb[(bh << 16) + (n << 6) + d] = f2bf(v * SCALE);
                    else if (which == 1) kb[(bh << 16) + (n << 6) + d] = f2bf(v);
                    else                 vtb[(bh << 16) + (d << 10) + n] = f2bf(v);
                } else {
                    outp[(size_t)r * 768 + c] = v + bias[c];
                }
            }
        }
    }
}

// ---------- attention pass 1: barrier-free TRANSPOSED denominator ----------
// den5 == den3 (best den so far) with MFMA operand order swapped: S^T = K·Q^T,
// so the stored inv_den (lane,reg) convention becomes (n=l16, m=quad*4+reg),
// matching pv5's S^T stream. Wave tile 64x64, NO LDS, NO barriers, frags from
// XCD-local L2 (b = bid&7). Q pre-scaled -> den += exp(s) directly.
__global__ __launch_bounds__(256, 2)
void attn_den5(const short* __restrict__ qb, const short* __restrict__ kb,
               short* __restrict__ invp) {
    const int tid = threadIdx.x, lane = tid & 63, wv = tid >> 6;
    const int quad = lane >> 4, l16 = lane & 15;
    const int b = blockIdx.x & 7;
    const int t = blockIdx.x >> 3;       // 0..63
    const int nb = t >> 3, mb = t & 7;   // 128x128 block tile
    const int n0 = (nb << 7) + ((wv >> 1) << 6);
    const int m0 = (mb << 7) + ((wv & 1) << 6);

    f32x4 den[4][4];                     // [mt][nt], S^T convention
#pragma unroll
    for (int i = 0; i < 4; i++)
#pragma unroll
        for (int j = 0; j < 4; j++) den[i][j] = (f32x4){0.f, 0.f, 0.f, 0.f};
    const f32x4 z = (f32x4){0.f, 0.f, 0.f, 0.f};

    for (int h = 0; h < HH; h++) {
        const short* qp = qb + ((b * HH + h) << 16);
        const short* kp = kb + ((b * HH + h) << 16);
        bf16x8 ka[4][2], qf[4][2];       // A from K rows (m), B from Q rows (n)
#pragma unroll
        for (int mt = 0; mt < 4; mt++) {
            const short* p = kp + ((m0 + mt * 16 + l16) << 6) + quad * 8;
            ka[mt][0] = *reinterpret_cast<const bf16x8*>(p);
            ka[mt][1] = *reinterpret_cast<const bf16x8*>(p + 32);
        }
#pragma unroll
        for (int nt = 0; nt < 4; nt++) {
            const short* p = qp + ((n0 + nt * 16 + l16) << 6) + quad * 8;
            qf[nt][0] = *reinterpret_cast<const bf16x8*>(p);
            qf[nt][1] = *reinterpret_cast<const bf16x8*>(p + 32);
        }
#pragma unroll
        for (int mt = 0; mt < 4; mt++)
#pragma unroll
            for (int nt = 0; nt < 4; nt++) {
                f32x4 s = MFMA16(ka[mt][0], qf[nt][0], z);   // S^T tile
                s = MFMA16(ka[mt][1], qf[nt][1], s);
#pragma unroll
                for (int r = 0; r < 4; r++) den[mt][nt][r] += __expf(s[r]);
            }
    }

    // write inv_den keyed by (ntg, mtg); (lane,reg) = (n=l16, m=quad*4+reg)
#pragma unroll
    for (int mt = 0; mt < 4; mt++)
#pragma unroll
        for (int nt = 0; nt < 4; nt++) {
            const int ntg = (n0 >> 4) + nt;
            const int mtg = (m0 >> 4) + mt;
            ushort4 o;
            o.x = (unsigned short)f2bf(1.0f / den[mt][nt][0]);
            o.y = (unsigned short)f2bf(1.0f / den[mt][nt][1]);
            o.z = (unsigned short)f2bf(1.0f / den[mt][nt][2]);
            o.w = (unsigned short)f2bf(1.0f / den[mt][nt][3]);
            *reinterpret_cast<ushort4*>(&invp[(((b * 64 + ntg) * 64 + mtg) * 64 + lane) * 4]) = o;
        }
}

// ---------- attention pass 2: transpose-free PV (zero LDS, zero fences) ----------
// Wave = (b, h, n32). S^T = K·Q^T lands in C-layout (row=m=quad*4+reg,
// col=n=l16) which IS the B-operand layout of mfma_f32_16x16x16 (col=lane&15,
// k=quad*4+j). So P^T = exp(S^T)*inv packs to a bf16x4 PV B-operand in
// registers; A-operand = Vt[d][m] frag (row=d=l16, k=m=quad*4+j) loads
// straight from vtb. Whole iter is a free-running load->MFMA->VALU->MFMA
// stream with no LDS round-trip and no fence -> compiler can pipeline
// iterations (loads of iter i+1 in flight during iter i compute).
__global__ __launch_bounds__(256, 3)
void attn_pv5(const short* __restrict__ qb, const short* __restrict__ kb,
              const short* __restrict__ vtb, const short* __restrict__ invp,
              short* __restrict__ attn_out) {
    const int tid = threadIdx.x, lane = tid & 63, wv = tid >> 6;
    const int quad = lane >> 4, l16 = lane & 15;
    const int b = blockIdx.x & 7;
    const int r = blockIdx.x >> 3;       // 0..95
    const int h = r % 12;
    const int strip = r / 12;            // 0..7 (n128 strip)
    const int n0 = (strip << 7) + (wv << 5);
    const int bh = b * HH + h;

    // Q B-frags for 2 n16-tiles (col=n=l16, k=d=quad*8+j) — persistent
    bf16x8 qf[2][2];
#pragma unroll
    for (int nt = 0; nt < 2; nt++) {
        const short* qp = qb + (bh << 16) + ((n0 + nt * 16 + l16) << 6) + quad * 8;
        qf[nt][0] = *reinterpret_cast<const bf16x8*>(qp);
        qf[nt][1] = *reinterpret_cast<const bf16x8*>(qp + 32);
    }

    const f32x4 z = (f32x4){0.f, 0.f, 0.f, 0.f};
    f32x4 OT[2][4];                      // O^T[d][n] accumulators, [nt][dch]
#pragma unroll
    for (int nt = 0; nt < 2; nt++)
#pragma unroll
        for (int d = 0; d < 4; d++) OT[nt][d] = z;

    for (int it = 0; it < 32; it++) {
        const int m0 = it << 5;

        // K A-frags for two m16 halves (row=m=l16, k=d=quad*8+j)
        bf16x8 kf[2][2];
#pragma unroll
        for (int mh = 0; mh < 2; mh++) {
            const short* kp = kb + (bh << 16) + ((m0 + mh * 16 + l16) << 6) + quad * 8;
            kf[mh][0] = *reinterpret_cast<const bf16x8*>(kp);
            kf[mh][1] = *reinterpret_cast<const bf16x8*>(kp + 32);
        }
        // Vt A-frags for K=16 PV (row=d=l16, k=m=quad*4+j): 8B loads
        bf16x4 vf[2][4];
#pragma unroll
        for (int mh = 0; mh < 2; mh++)
#pragma unroll
            for (int dch = 0; dch < 4; dch++)
                vf[mh][dch] = *reinterpret_cast<const bf16x4*>(
                    vtb + (bh << 16) + ((dch * 16 + l16) << 10) + m0 + mh * 16 + quad * 4);

#pragma unroll
        for (int nt = 0; nt < 2; nt++) {
            const int ntg = (n0 >> 4) + nt;
#pragma unroll
            for (int mh = 0; mh < 2; mh++) {
                // S^T tile (Q pre-scaled by 1/8)
                f32x4 s = MFMA16(kf[mh][0], qf[nt][0], z);
                s = MFMA16(kf[mh][1], qf[nt][1], s);
                const int mtg = (m0 >> 4) + mh;
                const ushort4 iv = *reinterpret_cast<const ushort4*>(
                    &invp[(((b * 64 + ntg) * 64 + mtg) * 64 + lane) * 4]);
                bf16x4 pt;
                pt[0] = f2bf(__expf(s[0]) * bf2f(iv.x));
                pt[1] = f2bf(__expf(s[1]) * bf2f(iv.y));
                pt[2] = f2bf(__expf(s[2]) * bf2f(iv.z));
                pt[3] = f2bf(__expf(s[3]) * bf2f(iv.w));
                // PV: O^T[d][n] += Vt[d][m16] · P^T[m16][n]
#pragma unroll
                for (int dch = 0; dch < 4; dch++)
                    OT[nt][dch] = MFMA16K16(vf[mh][dch], pt, OT[nt][dch]);
            }
        }
    }

    // epilogue: O^T C-layout row=d=quad*4+reg, col=n=l16 -> 4 consecutive d
    // per lane -> one 8B store per (nt,dch)
#pragma unroll
    for (int nt = 0; nt < 2; nt++) {
        const size_t row = (size_t)((b << 10) + n0 + nt * 16 + l16) * 768;
#pragma unroll
        for (int dch = 0; dch < 4; dch++) {
            const int col = h * 64 + dch * 16 + quad * 4;
            ushort4 o;
            o.x = (unsigned short)f2bf(OT[nt][dch][0]);
            o.y = (unsigned short)f2bf(OT[nt][dch][1]);
            o.z = (unsigned short)f2bf(OT[nt][dch][2]);
            o.w = (unsigned short)f2bf(OT[nt][dch][3]);
            *reinterpret_cast<ushort4*>(&attn_out[row + col]) = o;
        }
    }
}

// ---------- launch ----------
extern "C" void kernel_launch(void* const* d_in, const int* in_sizes, int n_in,
                              void* d_out, int out_size, void* d_ws, size_t ws_size,
                              hipStream_t stream) {
    const float* x     = (const float*)d_in[0];
    const float* w_qkv = (const float*)d_in[1];
    const float* w_out = (const float*)d_in[2];
    const float* b_out = (const float*)d_in[3];
    float* out = (float*)d_out;

    short* xb   = (short*)d_ws;                 // [8192][768]
    short* wT1  = xb  + 8192 * 768;             // [2304][768]
    short* wT2  = wT1 + 2304 * 768;             // [768][768]
    short* qb   = wT2 + 768 * 768;              // [b][h][n][d]  (Q pre-scaled by 1/8)
    short* kb   = qb  + 96 * 65536;
    short* vtb  = kb  + 96 * 65536;             // [b][h][d][n]
    short* attn = vtb + 96 * 65536;             // [8192][768]
    short* invp = attn + 8192 * 768;            // [b][nt][mt][lane][4]  (S^T convention)

    cast_to_bf16<<<6144, 256, 0, stream>>>(x, xb, (8192 * 768) / 4);
    transpose_cast<<<(2304 * 768) / 256, 256, 0, stream>>>(w_qkv, wT1, 768, 2304);
    transpose_cast<<<(768 * 768) / 256, 256, 0, stream>>>(w_out, wT2, 768, 768);

    gemm128<0><<<dim3(2304 / 128, 8192 / 128), 256, 0, stream>>>(
        xb, wT1, 768, qb, kb, vtb, nullptr, nullptr);

    attn_den5<<<512, 256, 0, stream>>>(qb, kb, invp);
    attn_pv5<<<768, 256, 0, stream>>>(qb, kb, vtb, invp, attn);

    gemm128<1><<<dim3(768 / 128, 8192 / 128), 256, 0, stream>>>(
        attn, wT2, 768, nullptr, nullptr, nullptr, out, b_out);
}